// Round 5
// baseline (299.404 us; speedup 1.0000x reference)
//
#include <hip/hip_runtime.h>
#include <stdint.h>
#include <math.h>

// Problem constants (fixed by the reference)
constexpr int CB = 2;      // batch
constexpr int CS = 2048;   // seq (cutoff)
constexpr int CD = 1024;   // dmodel
constexpr int CE = 16;     // experts
constexpr int CK = 256;    // topk

typedef short bf16x8 __attribute__((ext_vector_type(8)));
typedef float f32x4 __attribute__((ext_vector_type(4)));

typedef __attribute__((address_space(1))) const unsigned int gu32;
typedef __attribute__((address_space(3))) unsigned int lu32;

__device__ __forceinline__ void async16(const void* g, void* l) {
    __builtin_amdgcn_global_load_lds((gu32*)g, (lu32*)l, 16, 0, 0);
}

__device__ inline unsigned short f2bf(float f) {
    union { float f; uint32_t u; } v; v.f = f;
    uint32_t u = v.u;
    uint32_t r = (u + 0x7FFFu + ((u >> 16) & 1u)) >> 16;
    return (unsigned short)r;
}

// ---------------- K1a: partial logits over a 64-d slice ----------------
__global__ __launch_bounds__(256)
void logits_part_kernel(const float* __restrict__ x,
                        const float* __restrict__ gate,
                        float* __restrict__ part) {
    const int tt = blockIdx.x;       // token tile (256 tokens)
    const int dt = blockIdx.y;       // d tile (64 d)
    const int tid = threadIdx.x;

    __shared__ float Xs[256 * 17];

    float acc[CE];
#pragma unroll
    for (int e = 0; e < CE; e++) acc[e] = 0.0f;

    const int tokl = tid >> 2;           // staging row within 64-token group
    const int c4 = (tid & 3) << 2;       // staging col (0,4,8,12)

    for (int dch = 0; dch < 4; dch++) {
        const int dbase = dt * 64 + dch * 16;
        __syncthreads();
#pragma unroll
        for (int q = 0; q < 4; q++) {
            const int tok = q * 64 + tokl;
            const f32x4 v = *(const f32x4*)(x + ((size_t)(tt * 256 + tok)) * CD + dbase + c4);
            Xs[tok * 17 + c4 + 0] = v[0];
            Xs[tok * 17 + c4 + 1] = v[1];
            Xs[tok * 17 + c4 + 2] = v[2];
            Xs[tok * 17 + c4 + 3] = v[3];
        }
        __syncthreads();
#pragma unroll
        for (int d = 0; d < 16; d++) {
            const float xv = Xs[tid * 17 + d];
            const float* gr = gate + (size_t)(dbase + d) * CE;  // wave-uniform
#pragma unroll
            for (int e = 0; e < CE; e++) acc[e] = fmaf(xv, gr[e], acc[e]);
        }
    }
    float* pr = part + ((size_t)dt * (CB * CS) + tt * 256 + tid) * CE;
#pragma unroll
    for (int e = 0; e < CE; e++) pr[e] = acc[e];
}

// ---------------- K1b: deterministic reduce of the 16 d-partials ----------------
__global__ __launch_bounds__(256)
void logits_reduce_kernel(const float* __restrict__ part,
                          float* __restrict__ logits) {
    const int i = blockIdx.x * 256 + threadIdx.x;   // 0 .. B*S*E-1
    float s = 0.0f;
#pragma unroll
    for (int p = 0; p < 16; p++) s += part[(size_t)p * (CB * CS * CE) + i];
    logits[i] = s;
}

// ---------------- K2: per (b,e) softmax over tokens + top-256 ----------------
__global__ void topk_kernel(const float* __restrict__ logits,
                            int* __restrict__ idx_out,
                            float* __restrict__ g_out) {
    const int be = blockIdx.x;            // b*E + e
    const int b = be >> 4, e = be & 15;
    const int tid = threadIdx.x;          // 256
    const int lane = tid & 63, wid = tid >> 6;

    __shared__ float redf[4];
    __shared__ int hist[256];
    __shared__ int wsum[4];
    __shared__ int sh_bin, sh_rank;
    __shared__ int scnt, eqc;
    __shared__ int eqbuf[CS];

    float lv[8], p[8];
    unsigned int uv[8];
#pragma unroll
    for (int j = 0; j < 8; j++) {
        const int s = tid + j * 256;
        lv[j] = logits[((size_t)(b * CS + s)) * CE + e];
    }
    float m = lv[0];
#pragma unroll
    for (int j = 1; j < 8; j++) m = fmaxf(m, lv[j]);
#pragma unroll
    for (int o = 32; o > 0; o >>= 1) m = fmaxf(m, __shfl_down(m, o));
    if (lane == 0) redf[wid] = m;
    __syncthreads();
    m = fmaxf(fmaxf(redf[0], redf[1]), fmaxf(redf[2], redf[3]));
    __syncthreads();
    float lsum = 0.0f;
#pragma unroll
    for (int j = 0; j < 8; j++) {
        p[j] = expf(lv[j] - m);
        uv[j] = __float_as_uint(p[j]);
        lsum += p[j];
    }
#pragma unroll
    for (int o = 32; o > 0; o >>= 1) lsum += __shfl_down(lsum, o);
    if (lane == 0) redf[wid] = lsum;
    __syncthreads();
    const float total = redf[0] + redf[1] + redf[2] + redf[3];
    const float inv_total = 1.0f / total;

    // ---- radix-256 select: find v = CK-th largest bit pattern ----
    unsigned int prefix = 0;
    int kneed = CK;
    for (int pass = 0; pass < 4; pass++) {
        const int shift = 24 - 8 * pass;
        __syncthreads();
        hist[tid] = 0;
        __syncthreads();
        const unsigned int hmask = (pass == 0) ? 0u : (0xFFFFFFFFu << (shift + 8));
#pragma unroll
        for (int j = 0; j < 8; j++)
            if ((uv[j] & hmask) == prefix)
                atomicAdd(&hist[(uv[j] >> shift) & 255], 1);
        __syncthreads();
        const int own = hist[tid];
        int s = own;
#pragma unroll
        for (int o = 1; o < 64; o <<= 1) {
            int t = __shfl_down(s, o);
            if (lane + o < 64) s += t;
        }
        if (lane == 0) wsum[wid] = s;
        __syncthreads();
        int above = 0;
        for (int ww = wid + 1; ww < 4; ww++) above += wsum[ww];
        const int incl = s + above;
        if (incl >= kneed && (incl - own) < kneed) {
            sh_bin = tid;
            sh_rank = kneed - (incl - own);
        }
        __syncthreads();
        prefix |= ((unsigned int)sh_bin) << shift;
        kneed = sh_rank;
    }
    const unsigned int v = prefix;
    const int quota = kneed;

    if (tid == 0) { scnt = 0; eqc = 0; }
    __syncthreads();
#pragma unroll
    for (int j = 0; j < 8; j++) {
        const int s = tid + j * 256;
        if (uv[j] > v) {
            const int pos = atomicAdd(&scnt, 1);
            idx_out[be * CK + pos] = s;
            g_out[be * CK + pos] = p[j] * inv_total;
        } else if (uv[j] == v) {
            const int pos = atomicAdd(&eqc, 1);
            eqbuf[pos] = s;
        }
    }
    __syncthreads();
    if (tid == 0) {
        const int cgt = scnt;
        const int n = eqc;
        const float gv = __uint_as_float(v) * inv_total;
        if (n > quota) {
            for (int i = 0; i < quota; i++) {
                int mn = i;
                for (int k2 = i + 1; k2 < n; k2++)
                    if (eqbuf[k2] < eqbuf[mn]) mn = k2;
                const int t2 = eqbuf[i]; eqbuf[i] = eqbuf[mn]; eqbuf[mn] = t2;
            }
        }
        for (int i = 0; i < quota; i++) {
            idx_out[be * CK + cgt + i] = eqbuf[i];
            g_out[be * CK + cgt + i] = gv;
        }
    }
}

// ---------------- K3: gather selected tokens, convert to bf16 ----------------
__global__ void gather_kernel(const float* __restrict__ x,
                              const int* __restrict__ idx_ws,
                              unsigned short* __restrict__ xinbuf) {
    const int row = blockIdx.x;            // be*CK + slot
    const int be = row >> 8;
    const int b = be >> 4;
    const int tok = idx_ws[row];
    const int c0 = threadIdx.x * 4;
    const f32x4 f = *(const f32x4*)(x + ((size_t)b * CS + tok) * CD + c0);
    union { unsigned short u[4]; uint2 v; } t;
    t.u[0] = f2bf(f[0]); t.u[1] = f2bf(f[1]); t.u[2] = f2bf(f[2]); t.u[3] = f2bf(f[3]);
    *(uint2*)(xinbuf + (size_t)row * CD + c0) = t.v;
}

// ---------------- K4: transpose+convert W[e][k][n] fp32 -> Wt[e][n][k] bf16 ----
__global__ __launch_bounds__(256)
void wt_kernel(const float* __restrict__ W, unsigned short* __restrict__ Wt) {
    const int kt = blockIdx.x, nt = blockIdx.y, e = blockIdx.z;
    const float* src = W + (size_t)e * CD * CD;
    unsigned short* dst = Wt + (size_t)e * CD * CD;
    const int tid = threadIdx.x;
    __shared__ unsigned short T[64 * 64];

    const int kr = tid >> 4;            // 0..15
    const int n4 = (tid & 15) << 2;     // 0,4,..,60
#pragma unroll
    for (int it = 0; it < 4; it++) {
        const int k = it * 16 + kr;                    // tile-local k 0..63
        const f32x4 v = *(const f32x4*)(src + (size_t)(kt * 64 + k) * CD + nt * 64 + n4);
        const int pp = k >> 4;                          // 16-short chunk 0..3
        const int klo = k & 15;
#pragma unroll
        for (int i = 0; i < 4; i++) {
            const int n = n4 + i;
            T[n * 64 + ((pp ^ ((n >> 2) & 3)) << 4) + klo] = f2bf(v[i]);
        }
    }
    __syncthreads();
    const int n = tid >> 2;             // 0..63
    const int pp = tid & 3;             // output k-chunk
    const int sw = pp ^ ((n >> 2) & 3);
    const uint4 a = *(const uint4*)&T[n * 64 + (sw << 4)];
    const uint4 b = *(const uint4*)&T[n * 64 + (sw << 4) + 8];
    unsigned short* drow = dst + (size_t)(nt * 64 + n) * CD + kt * 64 + pp * 16;
    *(uint4*)drow = a;
    *(uint4*)(drow + 8) = b;
}

// ---------------- K5/K6: batched GEMM 256x1024x1024 per (b,e) ------------------
// 128x64 tile, BK=32, double-buffered LDS with raw s_waitcnt/s_barrier
// pipelining: tile k+1's async16 loads stay in flight across the barrier
// (vmcnt(3) waits only the older batch), overlapping HBM latency with compute.
// LDS chunk swizzle: chunk c=(row,pos), global k-chunk kc = pos ^ ((row>>1)&3)
// -> frag ds_read_b128 lands 2-way (free).
template <int PHASE>
__global__ __launch_bounds__(256, 4)
void ffn_gemm(const unsigned short* __restrict__ Ain,
              const unsigned short* __restrict__ Wt,
              const float* __restrict__ bias,
              unsigned short* __restrict__ hout,
              const int* __restrict__ idx_ws,
              const float* __restrict__ g_ws,
              float* __restrict__ y) {
    const int mtile = blockIdx.x;   // 0..1
    const int ntile = blockIdx.y;   // 0..15
    const int z = blockIdx.z;       // 0..31 ; adjacent z share expert (L2 reuse)
    const int e = z >> 1, b = z & 1;
    const int be = b * 16 + e;
    const int tid = threadIdx.x;
    const int w = tid >> 6, l = tid & 63;
    const int wm = w & 1, wn = w >> 1;        // wave grid 2m x 2n (64m x 32n each)
    const int quad = l >> 4, lr = l & 15;

    __shared__ __align__(16) unsigned short As[2][128 * 32];  // 2 x 8 KB
    __shared__ __align__(16) unsigned short Bs[2][64 * 32];   // 2 x 4 KB

    f32x4 acc[4][2];
    const f32x4 zz = {0.f, 0.f, 0.f, 0.f};
#pragma unroll
    for (int mi = 0; mi < 4; mi++)
#pragma unroll
        for (int ni = 0; ni < 2; ni++) acc[mi][ni] = zz;

    const unsigned short* Abase = Ain + ((size_t)be * CK + mtile * 128) * CD;
    const unsigned short* Bbase = Wt + ((size_t)e * CD + ntile * 64) * CD;

    // staging chunk indices (precomputed): 3 async16 per thread per step
    int ac_row[2], ac_kc[2], ac_c[2];
#pragma unroll
    for (int j = 0; j < 2; j++) {
        const int c = (w * 2 + j) * 64 + l;        // 0..511
        ac_c[j] = c;
        ac_row[j] = c >> 2;
        ac_kc[j] = (c & 3) ^ ((ac_row[j] >> 1) & 3);
    }
    const int bc = w * 64 + l;                     // 0..255
    const int bc_row = bc >> 2;
    const int bc_kc = (bc & 3) ^ ((bc_row >> 1) & 3);

    // frag read swizzle: pos = quad ^ ((lr>>1)&3)  (rows are lr + mult of 16)
    const int fpos = (quad ^ ((lr >> 1) & 3)) * 8;

    // prologue: stage tile 0 into buffer 0
#pragma unroll
    for (int j = 0; j < 2; j++)
        async16(Abase + (size_t)ac_row[j] * CD + ac_kc[j] * 8, &As[0][ac_c[j] * 8]);
    async16(Bbase + (size_t)bc_row * CD + bc_kc * 8, &Bs[0][bc * 8]);

    for (int ks = 0; ks < 32; ks++) {
        const int cur = ks & 1;
        if (ks < 31) {
            const int nxt = cur ^ 1;
            const int k1 = (ks + 1) * 32;
#pragma unroll
            for (int j = 0; j < 2; j++)
                async16(Abase + (size_t)ac_row[j] * CD + k1 + ac_kc[j] * 8,
                        &As[nxt][ac_c[j] * 8]);
            async16(Bbase + (size_t)bc_row * CD + k1 + bc_kc * 8, &Bs[nxt][bc * 8]);
            asm volatile("s_waitcnt vmcnt(3)" ::: "memory");
        } else {
            asm volatile("s_waitcnt vmcnt(0)" ::: "memory");
        }
        asm volatile("s_barrier" ::: "memory");

        bf16x8 af[4], bfr[2];
#pragma unroll
        for (int mi = 0; mi < 4; mi++)
            af[mi] = *(const bf16x8*)&As[cur][(wm * 64 + mi * 16 + lr) * 32 + fpos];
#pragma unroll
        for (int ni = 0; ni < 2; ni++)
            bfr[ni] = *(const bf16x8*)&Bs[cur][(wn * 32 + ni * 16 + lr) * 32 + fpos];
#pragma unroll
        for (int mi = 0; mi < 4; mi++)
#pragma unroll
            for (int ni = 0; ni < 2; ni++)
                acc[mi][ni] = __builtin_amdgcn_mfma_f32_16x16x32_bf16(
                    af[mi], bfr[ni], acc[mi][ni], 0, 0, 0);

        asm volatile("s_barrier" ::: "memory");
    }

    // epilogue. C/D layout: col = lane&15, row = quad*4 + r  (m89/m91 verified)
    const int gn_base = ntile * 64 + wn * 32;
    if (PHASE == 0) {
#pragma unroll
        for (int mi = 0; mi < 4; mi++)
#pragma unroll
            for (int r = 0; r < 4; r++) {
                const int slot = mtile * 128 + wm * 64 + mi * 16 + quad * 4 + r;
                unsigned short* outrow = hout + ((size_t)be * CK + slot) * CD;
#pragma unroll
                for (int ni = 0; ni < 2; ni++) {
                    const int col = gn_base + ni * 16 + lr;
                    float hv = acc[mi][ni][r] + bias[e * CD + col];
                    hv = fmaxf(hv, 0.0f);
                    outrow[col] = f2bf(hv);
                }
            }
    } else {
#pragma unroll
        for (int mi = 0; mi < 4; mi++)
#pragma unroll
            for (int r = 0; r < 4; r++) {
                const int slot = mtile * 128 + wm * 64 + mi * 16 + quad * 4 + r;
                const int tok = idx_ws[be * CK + slot];
                const float gval = g_ws[be * CK + slot];
                float* yrow = y + ((size_t)b * CS + tok) * CD;
#pragma unroll
                for (int ni = 0; ni < 2; ni++) {
                    const int col = gn_base + ni * 16 + lr;
                    const float val = (acc[mi][ni][r] + bias[col]) * gval;
                    atomicAdd(&yrow[col], val);
                }
            }
    }
}

extern "C" void kernel_launch(void* const* d_in, const int* in_sizes, int n_in,
                              void* d_out, int out_size, void* d_ws, size_t ws_size,
                              hipStream_t stream) {
    const float* x    = (const float*)d_in[0];
    const float* gate = (const float*)d_in[1];
    const float* W1   = (const float*)d_in[2];
    const float* b1   = (const float*)d_in[3];
    const float* W2   = (const float*)d_in[4];
    const float* b2   = (const float*)d_in[5];
    float* y = (float*)d_out;

    // workspace layout (bytes):
    //   logits: 0         .. 262144     (B*S*E fp32)
    //   idx:    262144    .. +32768
    //   g:      294912    .. +32768
    //   xin:    327680    .. +16.78MB   (bf16)
    //   hbuf:   17104896  .. +16.78MB   (bf16)  [aliased: logits partials 4MB]
    //   Wt:     33882112  .. +33.55MB   (bf16, W1 then reused for W2)
    char* ws = (char*)d_ws;
    float* logits = (float*)ws;
    int* idxw = (int*)(ws + 262144);
    float* gw = (float*)(ws + 294912);
    unsigned short* xinbuf = (unsigned short*)(ws + 327680);
    unsigned short* hbuf = (unsigned short*)(ws + 17104896);
    float* partbuf = (float*)(ws + 17104896);   // lifetime disjoint from hbuf
    unsigned short* wtbuf = (unsigned short*)(ws + 33882112);

    logits_part_kernel<<<dim3(16, 16), 256, 0, stream>>>(x, gate, partbuf);
    logits_reduce_kernel<<<CB * CS * CE / 256, 256, 0, stream>>>(partbuf, logits);
    topk_kernel<<<CB * CE, 256, 0, stream>>>(logits, idxw, gw);
    gather_kernel<<<CB * CE * CK, 256, 0, stream>>>(x, idxw, xinbuf);
    wt_kernel<<<dim3(16, 16, CE), 256, 0, stream>>>(W1, wtbuf);
    hipMemsetAsync(d_out, 0, (size_t)CB * CS * CD * sizeof(float), stream);
    ffn_gemm<0><<<dim3(2, 16, CB * CE), 256, 0, stream>>>(xinbuf, wtbuf, b1, hbuf, idxw, gw, y);
    wt_kernel<<<dim3(16, 16, CE), 256, 0, stream>>>(W2, wtbuf);
    ffn_gemm<1><<<dim3(2, 16, CB * CE), 256, 0, stream>>>(hbuf, wtbuf, b2, nullptr, idxw, gw, y);
}

// Round 6
// 285.746 us; speedup vs baseline: 1.0478x; 1.0478x over previous
//
#include <hip/hip_runtime.h>
#include <stdint.h>
#include <math.h>

// Problem constants (fixed by the reference)
constexpr int CB = 2;      // batch
constexpr int CS = 2048;   // seq (cutoff)
constexpr int CD = 1024;   // dmodel
constexpr int CE = 16;     // experts
constexpr int CK = 256;    // topk

typedef short bf16x8 __attribute__((ext_vector_type(8)));
typedef float f32x4 __attribute__((ext_vector_type(4)));

typedef __attribute__((address_space(1))) const unsigned int gu32;
typedef __attribute__((address_space(3))) unsigned int lu32;
typedef __attribute__((address_space(3))) unsigned short lds_us;

__device__ __forceinline__ void async16(const void* g, lds_us* l) {
    __builtin_amdgcn_global_load_lds((gu32*)g, (lu32*)l, 16, 0, 0);
}

// ds_read_b128 hidden from the waitcnt legalizer (it would otherwise insert
// s_waitcnt vmcnt(0) before any visible LDS read aliasing the LDS-DMA).
__device__ __forceinline__ bf16x8 ds_read128(const lds_us* p) {
    bf16x8 v;
    asm volatile("ds_read_b128 %0, %1" : "=v"(v) : "v"(p));
    return v;
}

__device__ inline unsigned short f2bf(float f) {
    union { float f; uint32_t u; } v; v.f = f;
    uint32_t u = v.u;
    uint32_t r = (u + 0x7FFFu + ((u >> 16) & 1u)) >> 16;
    return (unsigned short)r;
}

// ---------------- K1a: partial logits over a 64-d slice ----------------
__global__ __launch_bounds__(256)
void logits_part_kernel(const float* __restrict__ x,
                        const float* __restrict__ gate,
                        float* __restrict__ part) {
    const int tt = blockIdx.x;       // token tile (256 tokens)
    const int dt = blockIdx.y;       // d tile (64 d)
    const int tid = threadIdx.x;

    __shared__ float Xs[256 * 17];

    float acc[CE];
#pragma unroll
    for (int e = 0; e < CE; e++) acc[e] = 0.0f;

    const int tokl = tid >> 2;           // staging row within 64-token group
    const int c4 = (tid & 3) << 2;       // staging col (0,4,8,12)

    for (int dch = 0; dch < 4; dch++) {
        const int dbase = dt * 64 + dch * 16;
        __syncthreads();
#pragma unroll
        for (int q = 0; q < 4; q++) {
            const int tok = q * 64 + tokl;
            const f32x4 v = *(const f32x4*)(x + ((size_t)(tt * 256 + tok)) * CD + dbase + c4);
            Xs[tok * 17 + c4 + 0] = v[0];
            Xs[tok * 17 + c4 + 1] = v[1];
            Xs[tok * 17 + c4 + 2] = v[2];
            Xs[tok * 17 + c4 + 3] = v[3];
        }
        __syncthreads();
#pragma unroll
        for (int d = 0; d < 16; d++) {
            const float xv = Xs[tid * 17 + d];
            const float* gr = gate + (size_t)(dbase + d) * CE;  // wave-uniform
#pragma unroll
            for (int e = 0; e < CE; e++) acc[e] = fmaf(xv, gr[e], acc[e]);
        }
    }
    float* pr = part + ((size_t)dt * (CB * CS) + tt * 256 + tid) * CE;
#pragma unroll
    for (int e = 0; e < CE; e++) pr[e] = acc[e];
}

// ---------------- K1b: deterministic reduce of the 16 d-partials ----------------
__global__ __launch_bounds__(256)
void logits_reduce_kernel(const float* __restrict__ part,
                          float* __restrict__ logits) {
    const int i = blockIdx.x * 256 + threadIdx.x;   // 0 .. B*S*E-1
    float s = 0.0f;
#pragma unroll
    for (int p = 0; p < 16; p++) s += part[(size_t)p * (CB * CS * CE) + i];
    logits[i] = s;
}

// ---------------- K2: per (b,e) softmax over tokens + top-256 ----------------
__global__ void topk_kernel(const float* __restrict__ logits,
                            int* __restrict__ idx_out,
                            float* __restrict__ g_out) {
    const int be = blockIdx.x;            // b*E + e
    const int b = be >> 4, e = be & 15;
    const int tid = threadIdx.x;          // 256
    const int lane = tid & 63, wid = tid >> 6;

    __shared__ float redf[4];
    __shared__ int hist[256];
    __shared__ int wsum[4];
    __shared__ int sh_bin, sh_rank;
    __shared__ int scnt, eqc;
    __shared__ int eqbuf[CS];

    float lv[8], p[8];
    unsigned int uv[8];
#pragma unroll
    for (int j = 0; j < 8; j++) {
        const int s = tid + j * 256;
        lv[j] = logits[((size_t)(b * CS + s)) * CE + e];
    }
    float m = lv[0];
#pragma unroll
    for (int j = 1; j < 8; j++) m = fmaxf(m, lv[j]);
#pragma unroll
    for (int o = 32; o > 0; o >>= 1) m = fmaxf(m, __shfl_down(m, o));
    if (lane == 0) redf[wid] = m;
    __syncthreads();
    m = fmaxf(fmaxf(redf[0], redf[1]), fmaxf(redf[2], redf[3]));
    __syncthreads();
    float lsum = 0.0f;
#pragma unroll
    for (int j = 0; j < 8; j++) {
        p[j] = expf(lv[j] - m);
        uv[j] = __float_as_uint(p[j]);
        lsum += p[j];
    }
#pragma unroll
    for (int o = 32; o > 0; o >>= 1) lsum += __shfl_down(lsum, o);
    if (lane == 0) redf[wid] = lsum;
    __syncthreads();
    const float total = redf[0] + redf[1] + redf[2] + redf[3];
    const float inv_total = 1.0f / total;

    // ---- radix-256 select: find v = CK-th largest bit pattern ----
    unsigned int prefix = 0;
    int kneed = CK;
    for (int pass = 0; pass < 4; pass++) {
        const int shift = 24 - 8 * pass;
        __syncthreads();
        hist[tid] = 0;
        __syncthreads();
        const unsigned int hmask = (pass == 0) ? 0u : (0xFFFFFFFFu << (shift + 8));
#pragma unroll
        for (int j = 0; j < 8; j++)
            if ((uv[j] & hmask) == prefix)
                atomicAdd(&hist[(uv[j] >> shift) & 255], 1);
        __syncthreads();
        const int own = hist[tid];
        int s = own;
#pragma unroll
        for (int o = 1; o < 64; o <<= 1) {
            int t = __shfl_down(s, o);
            if (lane + o < 64) s += t;
        }
        if (lane == 0) wsum[wid] = s;
        __syncthreads();
        int above = 0;
        for (int ww = wid + 1; ww < 4; ww++) above += wsum[ww];
        const int incl = s + above;
        if (incl >= kneed && (incl - own) < kneed) {
            sh_bin = tid;
            sh_rank = kneed - (incl - own);
        }
        __syncthreads();
        prefix |= ((unsigned int)sh_bin) << shift;
        kneed = sh_rank;
    }
    const unsigned int v = prefix;
    const int quota = kneed;

    if (tid == 0) { scnt = 0; eqc = 0; }
    __syncthreads();
#pragma unroll
    for (int j = 0; j < 8; j++) {
        const int s = tid + j * 256;
        if (uv[j] > v) {
            const int pos = atomicAdd(&scnt, 1);
            idx_out[be * CK + pos] = s;
            g_out[be * CK + pos] = p[j] * inv_total;
        } else if (uv[j] == v) {
            const int pos = atomicAdd(&eqc, 1);
            eqbuf[pos] = s;
        }
    }
    __syncthreads();
    if (tid == 0) {
        const int cgt = scnt;
        const int n = eqc;
        const float gv = __uint_as_float(v) * inv_total;
        if (n > quota) {
            for (int i = 0; i < quota; i++) {
                int mn = i;
                for (int k2 = i + 1; k2 < n; k2++)
                    if (eqbuf[k2] < eqbuf[mn]) mn = k2;
                const int t2 = eqbuf[i]; eqbuf[i] = eqbuf[mn]; eqbuf[mn] = t2;
            }
        }
        for (int i = 0; i < quota; i++) {
            idx_out[be * CK + cgt + i] = eqbuf[i];
            g_out[be * CK + cgt + i] = gv;
        }
    }
}

// ---------------- K3: gather selected tokens, convert to bf16 ----------------
__global__ void gather_kernel(const float* __restrict__ x,
                              const int* __restrict__ idx_ws,
                              unsigned short* __restrict__ xinbuf) {
    const int row = blockIdx.x;            // be*CK + slot
    const int be = row >> 8;
    const int b = be >> 4;
    const int tok = idx_ws[row];
    const int c0 = threadIdx.x * 4;
    const f32x4 f = *(const f32x4*)(x + ((size_t)b * CS + tok) * CD + c0);
    union { unsigned short u[4]; uint2 v; } t;
    t.u[0] = f2bf(f[0]); t.u[1] = f2bf(f[1]); t.u[2] = f2bf(f[2]); t.u[3] = f2bf(f[3]);
    *(uint2*)(xinbuf + (size_t)row * CD + c0) = t.v;
}

// ---------------- K4: transpose+convert W[e][k][n] fp32 -> Wt[e][n][k] bf16 ----
__global__ __launch_bounds__(256)
void wt_kernel(const float* __restrict__ W, unsigned short* __restrict__ Wt) {
    const int kt = blockIdx.x, nt = blockIdx.y, e = blockIdx.z;
    const float* src = W + (size_t)e * CD * CD;
    unsigned short* dst = Wt + (size_t)e * CD * CD;
    const int tid = threadIdx.x;
    __shared__ unsigned short T[64 * 64];

    const int kr = tid >> 4;            // 0..15
    const int n4 = (tid & 15) << 2;     // 0,4,..,60
#pragma unroll
    for (int it = 0; it < 4; it++) {
        const int k = it * 16 + kr;                    // tile-local k 0..63
        const f32x4 v = *(const f32x4*)(src + (size_t)(kt * 64 + k) * CD + nt * 64 + n4);
        const int pp = k >> 4;                          // 16-short chunk 0..3
        const int klo = k & 15;
#pragma unroll
        for (int i = 0; i < 4; i++) {
            const int n = n4 + i;
            T[n * 64 + ((pp ^ ((n >> 2) & 3)) << 4) + klo] = f2bf(v[i]);
        }
    }
    __syncthreads();
    const int n = tid >> 2;             // 0..63
    const int pp = tid & 3;             // output k-chunk
    const int sw = pp ^ ((n >> 2) & 3);
    const uint4 a = *(const uint4*)&T[n * 64 + (sw << 4)];
    const uint4 b = *(const uint4*)&T[n * 64 + (sw << 4) + 8];
    unsigned short* drow = dst + (size_t)(nt * 64 + n) * CD + kt * 64 + pp * 16;
    *(uint4*)drow = a;
    *(uint4*)(drow + 8) = b;
}

// ---------------- K5/K6: batched GEMM 256x1024x1024 per (b,e) ------------------
// 128x64 tile, BK=32, 3-stage LDS ring, raw vmcnt(6)/s_barrier pipeline with
// asm ds_read_b128 (invisible to the waitcnt legalizer). XCD-aware decode:
// xcd = e&7 so all blocks of an expert share one XCD's L2 (W_e = 2MB fits).
template <int PHASE>
__global__ __launch_bounds__(256, 4)
void ffn_gemm(const unsigned short* __restrict__ Ain,
              const unsigned short* __restrict__ Wt,
              const float* __restrict__ bias,
              unsigned short* __restrict__ hout,
              const int* __restrict__ idx_ws,
              const float* __restrict__ g_ws,
              float* __restrict__ y) {
    const int id = blockIdx.x;                      // 0..1023, xcd = id&7
    const int e = (id & 7) | (((id >> 3) & 1) << 3);
    const int b = (id >> 4) & 1;
    const int mtile = (id >> 5) & 1;
    const int ntile = id >> 6;                      // 0..15
    const int be = b * 16 + e;
    const int tid = threadIdx.x;
    const int w = tid >> 6, l = tid & 63;
    const int wm = w & 1, wn = w >> 1;              // wave grid 2m x 2n
    const int quad = l >> 4, lr = l & 15;

    __shared__ __align__(16) unsigned short As_s[3][128 * 32];  // 3 x 8 KB
    __shared__ __align__(16) unsigned short Bs_s[3][64 * 32];   // 3 x 4 KB

    f32x4 acc[4][2];
    const f32x4 zz = {0.f, 0.f, 0.f, 0.f};
#pragma unroll
    for (int mi = 0; mi < 4; mi++)
#pragma unroll
        for (int ni = 0; ni < 2; ni++) acc[mi][ni] = zz;

    const unsigned short* Abase = Ain + ((size_t)be * CK + mtile * 128) * CD;
    const unsigned short* Bbase = Wt + ((size_t)e * CD + ntile * 64) * CD;

    // staging chunk indices: 3 async16 per thread per stage (2 A + 1 B)
    int ac_c[2];
    size_t ag[2];
#pragma unroll
    for (int j = 0; j < 2; j++) {
        const int c = (w * 2 + j) * 64 + l;        // 0..511
        ac_c[j] = c;
        const int row = c >> 2;
        const int kc = (c & 3) ^ ((row >> 1) & 3); // global-side swizzle
        ag[j] = (size_t)row * CD + kc * 8;
    }
    const int bc = w * 64 + l;                     // 0..255
    const int brow = bc >> 2;
    const size_t bg = (size_t)brow * CD + ((bc & 3) ^ ((brow >> 1) & 3)) * 8;

    // frag read swizzle: pos = quad ^ ((lr>>1)&3)
    const int fpos = (quad ^ ((lr >> 1) & 3)) * 8;

    lds_us* pa0 = (lds_us*)As_s[0]; lds_us* pa1 = (lds_us*)As_s[1]; lds_us* pa2 = (lds_us*)As_s[2];
    lds_us* pb0 = (lds_us*)Bs_s[0]; lds_us* pb1 = (lds_us*)Bs_s[1]; lds_us* pb2 = (lds_us*)Bs_s[2];

    // prologue: tiles 0,1 -> buffers 0,1
#pragma unroll
    for (int j = 0; j < 2; j++) async16(Abase + ag[j], pa0 + ac_c[j] * 8);
    async16(Bbase + bg, pb0 + bc * 8);
#pragma unroll
    for (int j = 0; j < 2; j++) async16(Abase + ag[j] + 32, pa1 + ac_c[j] * 8);
    async16(Bbase + bg + 32, pb1 + bc * 8);

    for (int ks = 0; ks < 32; ks++) {
        if (ks < 30) {
            const int k2 = (ks + 2) * 32;
#pragma unroll
            for (int j = 0; j < 2; j++) async16(Abase + ag[j] + k2, pa2 + ac_c[j] * 8);
            async16(Bbase + bg + k2, pb2 + bc * 8);
            asm volatile("s_waitcnt vmcnt(6)" ::: "memory");
        } else if (ks == 30) {
            asm volatile("s_waitcnt vmcnt(3)" ::: "memory");
        } else {
            asm volatile("s_waitcnt vmcnt(0)" ::: "memory");
        }
        asm volatile("s_barrier" ::: "memory");

        bf16x8 af[4], bfr[2];
#pragma unroll
        for (int mi = 0; mi < 4; mi++)
            af[mi] = ds_read128(pa0 + (wm * 64 + mi * 16 + lr) * 32 + fpos);
#pragma unroll
        for (int ni = 0; ni < 2; ni++)
            bfr[ni] = ds_read128(pb0 + (wn * 32 + ni * 16 + lr) * 32 + fpos);
        // wait for the ds_reads, tying the fragment registers so MFMA can't hoist
        asm volatile("s_waitcnt lgkmcnt(0)"
                     : "+v"(af[0]), "+v"(af[1]), "+v"(af[2]), "+v"(af[3]),
                       "+v"(bfr[0]), "+v"(bfr[1])
                     :: "memory");
#pragma unroll
        for (int mi = 0; mi < 4; mi++)
#pragma unroll
            for (int ni = 0; ni < 2; ni++)
                acc[mi][ni] = __builtin_amdgcn_mfma_f32_16x16x32_bf16(
                    af[mi], bfr[ni], acc[mi][ni], 0, 0, 0);

        asm volatile("s_barrier" ::: "memory");
        // rotate ring: (compute, ready, fill) <- (ready, fill, compute)
        lds_us* t = pa0; pa0 = pa1; pa1 = pa2; pa2 = t;
        t = pb0; pb0 = pb1; pb1 = pb2; pb2 = t;
    }

    // epilogue. C/D layout: col = lane&15, row = quad*4 + r  (m89/m91 verified)
    const int gn_base = ntile * 64 + wn * 32;
    if (PHASE == 0) {
#pragma unroll
        for (int mi = 0; mi < 4; mi++)
#pragma unroll
            for (int r = 0; r < 4; r++) {
                const int slot = mtile * 128 + wm * 64 + mi * 16 + quad * 4 + r;
                unsigned short* outrow = hout + ((size_t)be * CK + slot) * CD;
#pragma unroll
                for (int ni = 0; ni < 2; ni++) {
                    const int col = gn_base + ni * 16 + lr;
                    float hv = acc[mi][ni][r] + bias[e * CD + col];
                    hv = fmaxf(hv, 0.0f);
                    outrow[col] = f2bf(hv);
                }
            }
    } else {
#pragma unroll
        for (int mi = 0; mi < 4; mi++)
#pragma unroll
            for (int r = 0; r < 4; r++) {
                const int slot = mtile * 128 + wm * 64 + mi * 16 + quad * 4 + r;
                const int tok = idx_ws[be * CK + slot];
                const float gval = g_ws[be * CK + slot];
                float* yrow = y + ((size_t)b * CS + tok) * CD;
#pragma unroll
                for (int ni = 0; ni < 2; ni++) {
                    const int col = gn_base + ni * 16 + lr;
                    const float val = (acc[mi][ni][r] + bias[col]) * gval;
                    atomicAdd(&yrow[col], val);
                }
            }
    }
}

extern "C" void kernel_launch(void* const* d_in, const int* in_sizes, int n_in,
                              void* d_out, int out_size, void* d_ws, size_t ws_size,
                              hipStream_t stream) {
    const float* x    = (const float*)d_in[0];
    const float* gate = (const float*)d_in[1];
    const float* W1   = (const float*)d_in[2];
    const float* b1   = (const float*)d_in[3];
    const float* W2   = (const float*)d_in[4];
    const float* b2   = (const float*)d_in[5];
    float* y = (float*)d_out;

    // workspace layout (bytes):
    //   logits: 0         .. 262144     (B*S*E fp32)
    //   idx:    262144    .. +32768
    //   g:      294912    .. +32768
    //   xin:    327680    .. +16.78MB   (bf16)
    //   hbuf:   17104896  .. +16.78MB   (bf16)  [aliased: logits partials 4MB]
    //   Wt:     33882112  .. +33.55MB   (bf16, W1 then reused for W2)
    char* ws = (char*)d_ws;
    float* logits = (float*)ws;
    int* idxw = (int*)(ws + 262144);
    float* gw = (float*)(ws + 294912);
    unsigned short* xinbuf = (unsigned short*)(ws + 327680);
    unsigned short* hbuf = (unsigned short*)(ws + 17104896);
    float* partbuf = (float*)(ws + 17104896);   // lifetime disjoint from hbuf
    unsigned short* wtbuf = (unsigned short*)(ws + 33882112);

    logits_part_kernel<<<dim3(16, 16), 256, 0, stream>>>(x, gate, partbuf);
    logits_reduce_kernel<<<CB * CS * CE / 256, 256, 0, stream>>>(partbuf, logits);
    topk_kernel<<<CB * CE, 256, 0, stream>>>(logits, idxw, gw);
    gather_kernel<<<CB * CE * CK, 256, 0, stream>>>(x, idxw, xinbuf);
    wt_kernel<<<dim3(16, 16, CE), 256, 0, stream>>>(W1, wtbuf);
    hipMemsetAsync(d_out, 0, (size_t)CB * CS * CD * sizeof(float), stream);
    ffn_gemm<0><<<1024, 256, 0, stream>>>(xinbuf, wtbuf, b1, hbuf, idxw, gw, y);
    wt_kernel<<<dim3(16, 16, CE), 256, 0, stream>>>(W2, wtbuf);
    ffn_gemm<1><<<1024, 256, 0, stream>>>(hbuf, wtbuf, b2, nullptr, idxw, gw, y);
}

// Round 7
// 282.126 us; speedup vs baseline: 1.0612x; 1.0128x over previous
//
#include <hip/hip_runtime.h>
#include <stdint.h>
#include <math.h>

// Problem constants (fixed by the reference)
constexpr int CB = 2;      // batch
constexpr int CS = 2048;   // seq (cutoff)
constexpr int CD = 1024;   // dmodel
constexpr int CE = 16;     // experts
constexpr int CK = 256;    // topk

typedef short bf16x8 __attribute__((ext_vector_type(8)));
typedef float f32x4 __attribute__((ext_vector_type(4)));

typedef __attribute__((address_space(1))) const unsigned int gu32;
typedef __attribute__((address_space(3))) unsigned int lu32;
typedef __attribute__((address_space(3))) unsigned short lds_us;

__device__ __forceinline__ void async16(const void* g, lds_us* l) {
    __builtin_amdgcn_global_load_lds((gu32*)g, (lu32*)l, 16, 0, 0);
}

// ds_read_b128 hidden from the waitcnt legalizer (it would otherwise insert
// s_waitcnt vmcnt(0) before any visible LDS read aliasing the LDS-DMA).
__device__ __forceinline__ bf16x8 ds_read128(const lds_us* p) {
    bf16x8 v;
    asm volatile("ds_read_b128 %0, %1" : "=v"(v) : "v"(p));
    return v;
}

__device__ inline unsigned short f2bf(float f) {
    union { float f; uint32_t u; } v; v.f = f;
    uint32_t u = v.u;
    uint32_t r = (u + 0x7FFFu + ((u >> 16) & 1u)) >> 16;
    return (unsigned short)r;
}

// ---------------- K1a: partial logits over a 64-d slice ----------------
__global__ __launch_bounds__(256)
void logits_part_kernel(const float* __restrict__ x,
                        const float* __restrict__ gate,
                        float* __restrict__ part) {
    const int tt = blockIdx.x;       // token tile (256 tokens)
    const int dt = blockIdx.y;       // d tile (64 d)
    const int tid = threadIdx.x;

    __shared__ float Xs[256 * 17];

    float acc[CE];
#pragma unroll
    for (int e = 0; e < CE; e++) acc[e] = 0.0f;

    const int tokl = tid >> 2;           // staging row within 64-token group
    const int c4 = (tid & 3) << 2;       // staging col (0,4,8,12)

    for (int dch = 0; dch < 4; dch++) {
        const int dbase = dt * 64 + dch * 16;
        __syncthreads();
#pragma unroll
        for (int q = 0; q < 4; q++) {
            const int tok = q * 64 + tokl;
            const f32x4 v = *(const f32x4*)(x + ((size_t)(tt * 256 + tok)) * CD + dbase + c4);
            Xs[tok * 17 + c4 + 0] = v[0];
            Xs[tok * 17 + c4 + 1] = v[1];
            Xs[tok * 17 + c4 + 2] = v[2];
            Xs[tok * 17 + c4 + 3] = v[3];
        }
        __syncthreads();
#pragma unroll
        for (int d = 0; d < 16; d++) {
            const float xv = Xs[tid * 17 + d];
            const float* gr = gate + (size_t)(dbase + d) * CE;  // wave-uniform
#pragma unroll
            for (int e = 0; e < CE; e++) acc[e] = fmaf(xv, gr[e], acc[e]);
        }
    }
    float* pr = part + ((size_t)dt * (CB * CS) + tt * 256 + tid) * CE;
#pragma unroll
    for (int e = 0; e < CE; e++) pr[e] = acc[e];
}

// ---------------- K1b: deterministic reduce of the 16 d-partials ----------------
__global__ __launch_bounds__(256)
void logits_reduce_kernel(const float* __restrict__ part,
                          float* __restrict__ logits) {
    const int i = blockIdx.x * 256 + threadIdx.x;   // 0 .. B*S*E-1
    float s = 0.0f;
#pragma unroll
    for (int p = 0; p < 16; p++) s += part[(size_t)p * (CB * CS * CE) + i];
    logits[i] = s;
}

// ---------------- K2: per (b,e) softmax over tokens + top-256 ----------------
__global__ void topk_kernel(const float* __restrict__ logits,
                            int* __restrict__ idx_out,
                            float* __restrict__ g_out) {
    const int be = blockIdx.x;            // b*E + e
    const int b = be >> 4, e = be & 15;
    const int tid = threadIdx.x;          // 256
    const int lane = tid & 63, wid = tid >> 6;

    __shared__ float redf[4];
    __shared__ int hist[256];
    __shared__ int wsum[4];
    __shared__ int sh_bin, sh_rank;
    __shared__ int scnt, eqc;
    __shared__ int eqbuf[CS];

    float lv[8], p[8];
    unsigned int uv[8];
#pragma unroll
    for (int j = 0; j < 8; j++) {
        const int s = tid + j * 256;
        lv[j] = logits[((size_t)(b * CS + s)) * CE + e];
    }
    float m = lv[0];
#pragma unroll
    for (int j = 1; j < 8; j++) m = fmaxf(m, lv[j]);
#pragma unroll
    for (int o = 32; o > 0; o >>= 1) m = fmaxf(m, __shfl_down(m, o));
    if (lane == 0) redf[wid] = m;
    __syncthreads();
    m = fmaxf(fmaxf(redf[0], redf[1]), fmaxf(redf[2], redf[3]));
    __syncthreads();
    float lsum = 0.0f;
#pragma unroll
    for (int j = 0; j < 8; j++) {
        p[j] = expf(lv[j] - m);
        uv[j] = __float_as_uint(p[j]);
        lsum += p[j];
    }
#pragma unroll
    for (int o = 32; o > 0; o >>= 1) lsum += __shfl_down(lsum, o);
    if (lane == 0) redf[wid] = lsum;
    __syncthreads();
    const float total = redf[0] + redf[1] + redf[2] + redf[3];
    const float inv_total = 1.0f / total;

    // ---- radix-256 select: find v = CK-th largest bit pattern ----
    unsigned int prefix = 0;
    int kneed = CK;
    for (int pass = 0; pass < 4; pass++) {
        const int shift = 24 - 8 * pass;
        __syncthreads();
        hist[tid] = 0;
        __syncthreads();
        const unsigned int hmask = (pass == 0) ? 0u : (0xFFFFFFFFu << (shift + 8));
#pragma unroll
        for (int j = 0; j < 8; j++)
            if ((uv[j] & hmask) == prefix)
                atomicAdd(&hist[(uv[j] >> shift) & 255], 1);
        __syncthreads();
        const int own = hist[tid];
        int s = own;
#pragma unroll
        for (int o = 1; o < 64; o <<= 1) {
            int t = __shfl_down(s, o);
            if (lane + o < 64) s += t;
        }
        if (lane == 0) wsum[wid] = s;
        __syncthreads();
        int above = 0;
        for (int ww = wid + 1; ww < 4; ww++) above += wsum[ww];
        const int incl = s + above;
        if (incl >= kneed && (incl - own) < kneed) {
            sh_bin = tid;
            sh_rank = kneed - (incl - own);
        }
        __syncthreads();
        prefix |= ((unsigned int)sh_bin) << shift;
        kneed = sh_rank;
    }
    const unsigned int v = prefix;
    const int quota = kneed;

    if (tid == 0) { scnt = 0; eqc = 0; }
    __syncthreads();
#pragma unroll
    for (int j = 0; j < 8; j++) {
        const int s = tid + j * 256;
        if (uv[j] > v) {
            const int pos = atomicAdd(&scnt, 1);
            idx_out[be * CK + pos] = s;
            g_out[be * CK + pos] = p[j] * inv_total;
        } else if (uv[j] == v) {
            const int pos = atomicAdd(&eqc, 1);
            eqbuf[pos] = s;
        }
    }
    __syncthreads();
    if (tid == 0) {
        const int cgt = scnt;
        const int n = eqc;
        const float gv = __uint_as_float(v) * inv_total;
        if (n > quota) {
            for (int i = 0; i < quota; i++) {
                int mn = i;
                for (int k2 = i + 1; k2 < n; k2++)
                    if (eqbuf[k2] < eqbuf[mn]) mn = k2;
                const int t2 = eqbuf[i]; eqbuf[i] = eqbuf[mn]; eqbuf[mn] = t2;
            }
        }
        for (int i = 0; i < quota; i++) {
            idx_out[be * CK + cgt + i] = eqbuf[i];
            g_out[be * CK + cgt + i] = gv;
        }
    }
}

// ---------------- K3: gather selected tokens, convert to bf16 ----------------
__global__ void gather_kernel(const float* __restrict__ x,
                              const int* __restrict__ idx_ws,
                              unsigned short* __restrict__ xinbuf) {
    const int row = blockIdx.x;            // be*CK + slot
    const int be = row >> 8;
    const int b = be >> 4;
    const int tok = idx_ws[row];
    const int c0 = threadIdx.x * 4;
    const f32x4 f = *(const f32x4*)(x + ((size_t)b * CS + tok) * CD + c0);
    union { unsigned short u[4]; uint2 v; } t;
    t.u[0] = f2bf(f[0]); t.u[1] = f2bf(f[1]); t.u[2] = f2bf(f[2]); t.u[3] = f2bf(f[3]);
    *(uint2*)(xinbuf + (size_t)row * CD + c0) = t.v;
}

// ---------------- K4: transpose+convert W[e][k][n] fp32 -> Wt[e][n][k] bf16 ----
__global__ __launch_bounds__(256)
void wt_kernel(const float* __restrict__ W, unsigned short* __restrict__ Wt) {
    const int kt = blockIdx.x, nt = blockIdx.y, e = blockIdx.z;
    const float* src = W + (size_t)e * CD * CD;
    unsigned short* dst = Wt + (size_t)e * CD * CD;
    const int tid = threadIdx.x;
    __shared__ unsigned short T[64 * 64];

    const int kr = tid >> 4;            // 0..15
    const int n4 = (tid & 15) << 2;     // 0,4,..,60
#pragma unroll
    for (int it = 0; it < 4; it++) {
        const int k = it * 16 + kr;                    // tile-local k 0..63
        const f32x4 v = *(const f32x4*)(src + (size_t)(kt * 64 + k) * CD + nt * 64 + n4);
        const int pp = k >> 4;                          // 16-short chunk 0..3
        const int klo = k & 15;
#pragma unroll
        for (int i = 0; i < 4; i++) {
            const int n = n4 + i;
            T[n * 64 + ((pp ^ ((n >> 2) & 3)) << 4) + klo] = f2bf(v[i]);
        }
    }
    __syncthreads();
    const int n = tid >> 2;             // 0..63
    const int pp = tid & 3;             // output k-chunk
    const int sw = pp ^ ((n >> 2) & 3);
    const uint4 a = *(const uint4*)&T[n * 64 + (sw << 4)];
    const uint4 b = *(const uint4*)&T[n * 64 + (sw << 4) + 8];
    unsigned short* drow = dst + (size_t)(nt * 64 + n) * CD + kt * 64 + pp * 16;
    *(uint4*)drow = a;
    *(uint4*)(drow + 8) = b;
}

// ---------------- K5/K6: batched GEMM 256x1024x1024 per (b,e) ------------------
// 128x128 tile, BK=32, 3-stage LDS ring (48 KB), raw vmcnt(8)/s_barrier
// pipeline with asm ds_read_b128. 4 waves, each computing 64x64 (4x4 MFMA).
// XCD-aware decode: xcd = e&7 so an expert's 32 blocks share one XCD L2.
template <int PHASE>
__global__ __launch_bounds__(256, 2)
void ffn_gemm(const unsigned short* __restrict__ Ain,
              const unsigned short* __restrict__ Wt,
              const float* __restrict__ bias,
              unsigned short* __restrict__ hout,
              const int* __restrict__ idx_ws,
              const float* __restrict__ g_ws,
              float* __restrict__ y) {
    const int id = blockIdx.x;                      // 0..511, xcd = id&7
    const int e = (id & 7) | (((id >> 3) & 1) << 3);
    const int b = (id >> 4) & 1;
    const int mtile = (id >> 5) & 1;
    const int ntile = id >> 6;                      // 0..7
    const int be = b * 16 + e;
    const int tid = threadIdx.x;
    const int w = tid >> 6, l = tid & 63;
    const int wm = w & 1, wn = w >> 1;              // wave grid 2x2, 64x64 each
    const int quad = l >> 4, lr = l & 15;

    __shared__ __align__(16) unsigned short As_s[3][128 * 32];  // 3 x 8 KB
    __shared__ __align__(16) unsigned short Bs_s[3][128 * 32];  // 3 x 8 KB

    f32x4 acc[4][4];
    const f32x4 zz = {0.f, 0.f, 0.f, 0.f};
#pragma unroll
    for (int mi = 0; mi < 4; mi++)
#pragma unroll
        for (int ni = 0; ni < 4; ni++) acc[mi][ni] = zz;

    const unsigned short* Abase = Ain + ((size_t)be * CK + mtile * 128) * CD;
    const unsigned short* Bbase = Wt + ((size_t)e * CD + ntile * 128) * CD;

    // staging: 128 rows x 4 chunks = 512 chunks per operand; 2 instr/thread each
    int c_c[2];
    size_t goff[2];
#pragma unroll
    for (int j = 0; j < 2; j++) {
        const int c = (w + j * 4) * 64 + l;        // 0..511
        c_c[j] = c;
        const int row = c >> 2;
        const int kc = (c & 3) ^ ((row >> 1) & 3); // global-side swizzle
        goff[j] = (size_t)row * CD + kc * 8;
    }

    // frag read swizzle: pos = quad ^ ((lr>>1)&3)
    const int fpos = (quad ^ ((lr >> 1) & 3)) * 8;

    lds_us* pa0 = (lds_us*)As_s[0]; lds_us* pa1 = (lds_us*)As_s[1]; lds_us* pa2 = (lds_us*)As_s[2];
    lds_us* pb0 = (lds_us*)Bs_s[0]; lds_us* pb1 = (lds_us*)Bs_s[1]; lds_us* pb2 = (lds_us*)Bs_s[2];

    // prologue: tiles 0,1 -> buffers 0,1  (4 instr per stage per thread)
#pragma unroll
    for (int j = 0; j < 2; j++) {
        async16(Abase + goff[j], pa0 + c_c[j] * 8);
        async16(Bbase + goff[j], pb0 + c_c[j] * 8);
    }
#pragma unroll
    for (int j = 0; j < 2; j++) {
        async16(Abase + goff[j] + 32, pa1 + c_c[j] * 8);
        async16(Bbase + goff[j] + 32, pb1 + c_c[j] * 8);
    }

    for (int ks = 0; ks < 32; ks++) {
        if (ks < 30) {
            const int k2 = (ks + 2) * 32;
#pragma unroll
            for (int j = 0; j < 2; j++) {
                async16(Abase + goff[j] + k2, pa2 + c_c[j] * 8);
                async16(Bbase + goff[j] + k2, pb2 + c_c[j] * 8);
            }
            asm volatile("s_waitcnt vmcnt(8)" ::: "memory");
        } else if (ks == 30) {
            asm volatile("s_waitcnt vmcnt(4)" ::: "memory");
        } else {
            asm volatile("s_waitcnt vmcnt(0)" ::: "memory");
        }
        asm volatile("s_barrier" ::: "memory");

        bf16x8 af[4], bfr[4];
#pragma unroll
        for (int mi = 0; mi < 4; mi++)
            af[mi] = ds_read128(pa0 + (wm * 64 + mi * 16 + lr) * 32 + fpos);
#pragma unroll
        for (int ni = 0; ni < 4; ni++)
            bfr[ni] = ds_read128(pb0 + (wn * 64 + ni * 16 + lr) * 32 + fpos);
        asm volatile("s_waitcnt lgkmcnt(0)"
                     : "+v"(af[0]), "+v"(af[1]), "+v"(af[2]), "+v"(af[3]),
                       "+v"(bfr[0]), "+v"(bfr[1]), "+v"(bfr[2]), "+v"(bfr[3])
                     :: "memory");
#pragma unroll
        for (int mi = 0; mi < 4; mi++)
#pragma unroll
            for (int ni = 0; ni < 4; ni++)
                acc[mi][ni] = __builtin_amdgcn_mfma_f32_16x16x32_bf16(
                    af[mi], bfr[ni], acc[mi][ni], 0, 0, 0);

        asm volatile("s_barrier" ::: "memory");
        // rotate ring: (compute, ready, fill) <- (ready, fill, compute)
        lds_us* t = pa0; pa0 = pa1; pa1 = pa2; pa2 = t;
        t = pb0; pb0 = pb1; pb1 = pb2; pb2 = t;
    }

    // epilogue. C/D layout: col = lane&15, row = quad*4 + r  (m89/m91 verified)
    const int gn_base = ntile * 128 + wn * 64;
    if (PHASE == 0) {
#pragma unroll
        for (int mi = 0; mi < 4; mi++)
#pragma unroll
            for (int r = 0; r < 4; r++) {
                const int slot = mtile * 128 + wm * 64 + mi * 16 + quad * 4 + r;
                unsigned short* outrow = hout + ((size_t)be * CK + slot) * CD;
#pragma unroll
                for (int ni = 0; ni < 4; ni++) {
                    const int col = gn_base + ni * 16 + lr;
                    float hv = acc[mi][ni][r] + bias[e * CD + col];
                    hv = fmaxf(hv, 0.0f);
                    outrow[col] = f2bf(hv);
                }
            }
    } else {
#pragma unroll
        for (int mi = 0; mi < 4; mi++)
#pragma unroll
            for (int r = 0; r < 4; r++) {
                const int slot = mtile * 128 + wm * 64 + mi * 16 + quad * 4 + r;
                const int tok = idx_ws[be * CK + slot];
                const float gval = g_ws[be * CK + slot];
                float* yrow = y + ((size_t)b * CS + tok) * CD;
#pragma unroll
                for (int ni = 0; ni < 4; ni++) {
                    const int col = gn_base + ni * 16 + lr;
                    const float val = (acc[mi][ni][r] + bias[col]) * gval;
                    atomicAdd(&yrow[col], val);
                }
            }
    }
}

extern "C" void kernel_launch(void* const* d_in, const int* in_sizes, int n_in,
                              void* d_out, int out_size, void* d_ws, size_t ws_size,
                              hipStream_t stream) {
    const float* x    = (const float*)d_in[0];
    const float* gate = (const float*)d_in[1];
    const float* W1   = (const float*)d_in[2];
    const float* b1   = (const float*)d_in[3];
    const float* W2   = (const float*)d_in[4];
    const float* b2   = (const float*)d_in[5];
    float* y = (float*)d_out;

    // workspace layout (bytes):
    //   logits: 0         .. 262144     (B*S*E fp32)
    //   idx:    262144    .. +32768
    //   g:      294912    .. +32768
    //   xin:    327680    .. +16.78MB   (bf16)
    //   hbuf:   17104896  .. +16.78MB   (bf16)  [aliased: logits partials 4MB]
    //   Wt:     33882112  .. +33.55MB   (bf16, W1 then reused for W2)
    char* ws = (char*)d_ws;
    float* logits = (float*)ws;
    int* idxw = (int*)(ws + 262144);
    float* gw = (float*)(ws + 294912);
    unsigned short* xinbuf = (unsigned short*)(ws + 327680);
    unsigned short* hbuf = (unsigned short*)(ws + 17104896);
    float* partbuf = (float*)(ws + 17104896);   // lifetime disjoint from hbuf
    unsigned short* wtbuf = (unsigned short*)(ws + 33882112);

    logits_part_kernel<<<dim3(16, 16), 256, 0, stream>>>(x, gate, partbuf);
    logits_reduce_kernel<<<CB * CS * CE / 256, 256, 0, stream>>>(partbuf, logits);
    topk_kernel<<<CB * CE, 256, 0, stream>>>(logits, idxw, gw);
    gather_kernel<<<CB * CE * CK, 256, 0, stream>>>(x, idxw, xinbuf);
    wt_kernel<<<dim3(16, 16, CE), 256, 0, stream>>>(W1, wtbuf);
    hipMemsetAsync(d_out, 0, (size_t)CB * CS * CD * sizeof(float), stream);
    ffn_gemm<0><<<512, 256, 0, stream>>>(xinbuf, wtbuf, b1, hbuf, idxw, gw, y);
    wt_kernel<<<dim3(16, 16, CE), 256, 0, stream>>>(W2, wtbuf);
    ffn_gemm<1><<<512, 256, 0, stream>>>(hbuf, wtbuf, b2, nullptr, idxw, gw, y);
}